// Round 7
// baseline (535.267 us; speedup 1.0000x reference)
//
#include <hip/hip_runtime.h>

#define N 256
#define NLINE 4               // lines (waves) per block
#define NB (N / NLINE)        // 64 blocks
#define NT (NLINE * 64)       // 256 threads
#define LAM 0.05f             // step = ALPHA/2
#define TWOLAM (2.0f * LAM)
#define FOURLAM (4.0f * LAM)
#define MAXIT 35
#define TOL 0.01f

// broadcast-read one lane's register (lane index is wave-uniform -> v_readlane)
__device__ __forceinline__ float rlane(float v, int lane) {
    return __int_as_float(__builtin_amdgcn_readlane(__float_as_int(v), lane));
}

// 256-float line distributed over the wave: element k lives in lane (k>>2), reg (k&3)
struct Dist { float r0, r1, r2, r3; };

// branchless fetch: 4 independent readlanes + 2 uniform selects
__device__ __forceinline__ float dfetch(const Dist& d, int k) {
    const int lane = k >> 2;
    const int sel = k & 3;
    float a = rlane(d.r0, lane);
    float b = rlane(d.r1, lane);
    float c = rlane(d.r2, lane);
    float e = rlane(d.r3, lane);
    float ab = (sel & 1) ? b : a;
    float ce = (sel & 1) ? e : c;
    return (sel & 2) ? ce : ab;
}

// O(1) segment flush: o[j] = val for j in [lo, hi]
__device__ __forceinline__ void flushseg(Dist& o, int lo, int hi, float val, int lane) {
    const unsigned len = (unsigned)(hi - lo);
    const int base = 4 * lane - lo;
    o.r0 = ((unsigned)(base    ) <= len) ? val : o.r0;
    o.r1 = ((unsigned)(base + 1) <= len) ? val : o.r1;
    o.r2 = ((unsigned)(base + 2) <= len) ? val : o.r2;
    o.r3 = ((unsigned)(base + 3) <= len) ? val : o.r3;
}

// scalar 4-way select of a 64-bit mask (s_cselect_b64)
__device__ __forceinline__ unsigned long long sel4(unsigned long long a, unsigned long long b,
                                                   unsigned long long c, unsigned long long d, int r) {
    unsigned long long ab = (r & 1) ? b : a;
    unsigned long long cd = (r & 1) ? d : c;
    return (r & 2) ? cd : ab;
}

// first element >= jmin among set bits of per-reg masks (element j = 4*lane + reg)
__device__ __forceinline__ int firstel(unsigned long long m0, unsigned long long m1,
                                       unsigned long long m2, unsigned long long m3, int jmin) {
    int best = 256;
    int L0 = (jmin + 3) >> 2;
    unsigned long long a0 = m0 & ((L0 >= 64) ? 0ull : (~0ull << L0));
    if (a0) { int el = 4 * (int)__builtin_ctzll(a0);     best = el < best ? el : best; }
    int L1 = (jmin + 2) >> 2;
    unsigned long long a1 = m1 & ((L1 >= 64) ? 0ull : (~0ull << L1));
    if (a1) { int el = 4 * (int)__builtin_ctzll(a1) + 1; best = el < best ? el : best; }
    int L2 = (jmin + 1) >> 2;
    unsigned long long a2 = m2 & ((L2 >= 64) ? 0ull : (~0ull << L2));
    if (a2) { int el = 4 * (int)__builtin_ctzll(a2) + 2; best = el < best ? el : best; }
    int L3 = (jmin    ) >> 2;
    unsigned long long a3 = m3 & ((L3 >= 64) ? 0ull : (~0ull << L3));
    if (a3) { int el = 4 * (int)__builtin_ctzll(a3) + 3; best = el < best ? el : best; }
    return best;
}

// Condat's exact 1D TV prox — event-driven:
//  * between events the state advances in closed form via prefix sums C[j]
//    (umin(j) = umin + (C[j]-C[k]) - (j-k)*vmin); next event found lane-parallel
//  * runs of forced jumps (sign-aware 2lam/4lam condition) emitted in O(1) (FF)
__device__ void tv1d_scan(const Dist& v, Dist& o, const int lane)
{
    const float lam = LAM, mlam = -LAM, twolam = TWOLAM;

    // ---------- per-scan precompute (vectorized) ----------
    Dist vnx;                                    // vnx[j] = v[j+1] (j=255 garbage)
    vnx.r0 = v.r1; vnx.r1 = v.r2; vnx.r2 = v.r3;
    vnx.r3 = __shfl_down(v.r0, 1);
    Dist d;
    d.r0 = vnx.r0 - v.r0;  d.r1 = vnx.r1 - v.r1;
    d.r2 = vnx.r2 - v.r2;  d.r3 = vnx.r3 - v.r3;
    const unsigned lambits = __float_as_uint(lam);
    Dist sl;                                     // sl[j] = sign(d[j]) * lam
    sl.r0 = __uint_as_float((__float_as_uint(d.r0) & 0x80000000u) | lambits);
    sl.r1 = __uint_as_float((__float_as_uint(d.r1) & 0x80000000u) | lambits);
    sl.r2 = __uint_as_float((__float_as_uint(d.r2) & 0x80000000u) | lambits);
    sl.r3 = __uint_as_float((__float_as_uint(d.r3) & 0x80000000u) | lambits);
    Dist slp;                                    // slp[j] = sl[j-1], slp[0] = 0
    slp.r1 = sl.r0; slp.r2 = sl.r1; slp.r3 = sl.r2;
    {
        float s3u = __shfl_up(sl.r3, 1);
        slp.r0 = (lane == 0) ? 0.0f : s3u;
    }
    Dist e;                                      // e[j] = v[j] + sl[j] - slp[j]
    e.r0 = v.r0 + sl.r0 - slp.r0;
    e.r1 = v.r1 + sl.r1 - slp.r1;
    e.r2 = v.r2 + sl.r2 - slp.r2;
    e.r3 = v.r3 + sl.r3 - slp.r3;
    // sign & magnitude ballots
    const unsigned long long S0 = __ballot(d.r0 < 0.0f);
    const unsigned long long S1 = __ballot(d.r1 < 0.0f);
    const unsigned long long S2 = __ballot(d.r2 < 0.0f);
    const unsigned long long S3 = __ballot(d.r3 < 0.0f);
    const unsigned long long B2_0 = __ballot(fabsf(d.r0) > TWOLAM);
    const unsigned long long B2_1 = __ballot(fabsf(d.r1) > TWOLAM);
    const unsigned long long B2_2 = __ballot(fabsf(d.r2) > TWOLAM);
    const unsigned long long B2_3 = __ballot(fabsf(d.r3) > TWOLAM);
    const unsigned long long B4_0 = __ballot(fabsf(d.r0) > FOURLAM);
    const unsigned long long B4_1 = __ballot(fabsf(d.r1) > FOURLAM);
    const unsigned long long B4_2 = __ballot(fabsf(d.r2) > FOURLAM);
    const unsigned long long B4_3 = __ballot(fabsf(d.r3) > FOURLAM);
    // run-continuation: forced jump at j given run sign s[j-1]=sign(d[j-1]):
    // same-direction needs |d|>2lam, opposite needs |d|>4lam ->
    // F = B4 | (B2 & ~(S ^ Sprev));  Sprev shifts S by one element
    const unsigned long long Sp0 = (S3 << 1);    // j=0 bit irrelevant (never searched)
    const unsigned long long Sp1 = S0, Sp2 = S1, Sp3 = S2;
    const unsigned long long F0 = B4_0 | (B2_0 & ~(S0 ^ Sp0));
    const unsigned long long F1 = B4_1 | (B2_1 & ~(S1 ^ Sp1));
    const unsigned long long F2 = B4_2 | (B2_2 & ~(S2 ^ Sp2));
    const unsigned long long F3 = (B4_3 | (B2_3 & ~(S3 ^ Sp3))) & 0x7FFFFFFFFFFFFFFFull; // j=255 invalid
    // prefix sums C[j] (inclusive)
    float c0 = v.r0, c1 = c0 + v.r1, c2 = c1 + v.r2, c3 = c2 + v.r3;
    float sc = c3;
    #pragma unroll
    for (int off = 1; off < 64; off <<= 1) {
        float t = __shfl_up(sc, off);
        sc += (lane >= off) ? t : 0.0f;
    }
    const float cbase = sc - c3;
    Dist Cd; Cd.r0 = cbase + c0; Cd.r1 = cbase + c1; Cd.r2 = cbase + c2; Cd.r3 = cbase + c3;
    const float Ctot = rlane(Cd.r3, 63);
    Dist jf;                                     // element indices as floats
    jf.r0 = (float)(4 * lane); jf.r1 = jf.r0 + 1.0f; jf.r2 = jf.r0 + 2.0f; jf.r3 = jf.r0 + 3.0f;

    // ---------- state ----------
    int k = 0, k0 = 0, km = 0, kp = 0;
    float umin = lam, umax = mlam;
    const float v0 = rlane(v.r0, 0);
    float vmin = v0 - lam, vmax = v0 + lam;
    int guard = 0;

    // pre: standard-fresh at k, jump at element k+1 forced, k <= N-2
    auto fastfwd = [&]() {
        const int K1 = firstel(~F0, ~F1, ~F2, ~F3, k + 1);   // first non-forced j > k (<= 255)
        const int sneg = (int)((sel4(S0, S1, S2, S3, k & 3) >> (k >> 2)) & 1ull);
        flushseg(o, k, k, sneg ? vmin : vmax, lane);          // first run element
        if (K1 > k + 1) {                                     // (k, K1-1]: closed-form e[j]
            const int lo = k + 1;
            const unsigned len = (unsigned)(K1 - 1 - lo);
            const int base = 4 * lane - lo;
            o.r0 = ((unsigned)(base    ) <= len) ? e.r0 : o.r0;
            o.r1 = ((unsigned)(base + 1) <= len) ? e.r1 : o.r1;
            o.r2 = ((unsigned)(base + 2) <= len) ? e.r2 : o.r2;
            o.r3 = ((unsigned)(base + 3) <= len) ? e.r3 : o.r3;
        }
        k = K1; k0 = K1; km = K1; kp = K1;                    // fresh at K1, entry sign = S[K1-1]
        const float vK = dfetch(v, K1);
        const float sp = dfetch(slp, K1);                     // = sl[K1-1]
        vmin = vK - lam - sp;
        vmax = vmin + twolam;
        umin = lam; umax = mlam;
    };

    // init state: jump at element 1 forced iff |d0| > 3lam; use conservative 4lam bit
    if ((int)(B4_0 & 1ull)) fastfwd();

    for (;;) {
        if (++guard > 3000) return;                           // terminates; belt+suspenders
        if (k >= N - 1) {
            // boundary resolution at k == N-1 (verbatim semantics from verified R2/R6)
            for (;;) {
                if (++guard > 6000) return;
                if (umin < 0.0f) {                            // negative jump at boundary
                    flushseg(o, k0, km, vmin, lane);
                    k0 = km + 1;
                    if (k0 > N - 1) return;
                    km = k = k0;
                    vmin = dfetch(v, k0);
                    umin = lam;
                    umax = vmin + lam - vmax;
                } else if (umax > 0.0f) {                     // positive jump at boundary
                    flushseg(o, k0, kp, vmax, lane);
                    k0 = kp + 1;
                    if (k0 > N - 1) return;
                    kp = k = k0;
                    vmax = dfetch(v, k0);
                    umax = mlam;
                    umin = vmax - lam - vmin;
                } else {                                      // done: flush last segment
                    vmin += umin / (float)(k - k0 + 1);
                    flushseg(o, k0, k, vmin, lane);
                    return;
                }
                if (k != N - 1) break;
            }
            continue;                                         // resume events (quasi-fresh state)
        }
        // ---- lane-parallel next-event search from k ----
        // un(j) = An + C[j] - j*vmin ; ux(j) = Ax + C[j] - j*vmax
        const float Ck = dfetch(Cd, k);
        const float kfl = (float)k;
        const float An = fmaf(kfl, vmin, umin - Ck);
        const float Ax = fmaf(kfl, vmax, umax - Ck);
        const unsigned long long E0 = __ballot((fabsf(fmaf(jf.r0, -vmin, Cd.r0) + An) >= lam) |
                                               (fabsf(fmaf(jf.r0, -vmax, Cd.r0) + Ax) >= lam));
        const unsigned long long E1 = __ballot((fabsf(fmaf(jf.r1, -vmin, Cd.r1) + An) >= lam) |
                                               (fabsf(fmaf(jf.r1, -vmax, Cd.r1) + Ax) >= lam));
        const unsigned long long E2 = __ballot((fabsf(fmaf(jf.r2, -vmin, Cd.r2) + An) >= lam) |
                                               (fabsf(fmaf(jf.r2, -vmax, Cd.r2) + Ax) >= lam));
        const unsigned long long E3 = __ballot((fabsf(fmaf(jf.r3, -vmin, Cd.r3) + An) >= lam) |
                                               (fabsf(fmaf(jf.r3, -vmax, Cd.r3) + Ax) >= lam));
        const int js = firstel(E0, E1, E2, E3, k + 1);
        if (js > N - 1) {                                     // no event: advance to N-1
            umin = fmaf(255.0f, -vmin, Ctot) + An;
            umax = fmaf(255.0f, -vmax, Ctot) + Ax;
            k = N - 1;
            continue;
        }
        const float Cj = dfetch(Cd, js);
        const float jfl = (float)js;
        const float un = fmaf(jfl, -vmin, Cj) + An;
        const float ux = fmaf(jfl, -vmax, Cj) + Ax;
        const bool neg = un < mlam;
        const bool pos = ux > lam;
        if (neg | pos) {                                      // JUMP event at element js
            const float fval = neg ? vmin : vmax;
            const int   fhi  = neg ? km : kp;
            flushseg(o, k0, fhi, fval, lane);
            k0 = fhi + 1;                                     // may rewind (k0 < js) or be fresh (k0 == js)
            k = k0; km = k0; kp = k0;
            const float vstar = dfetch(v, k0);
            vmin = neg ? vstar : vstar - twolam;
            vmax = vmin + twolam;
            umin = lam; umax = mlam;
            if (k < N - 1) {                                  // try run fast-forward (sign-aware)
                const int kb = k >> 2, kr = k & 3;
                const int b4 = (int)((sel4(B4_0, B4_1, B4_2, B4_3, kr) >> kb) & 1ull);
                const int b2 = (int)((sel4(B2_0, B2_1, B2_2, B2_3, kr) >> kb) & 1ull);
                const int sk = (int)((sel4(S0, S1, S2, S3, kr) >> kb) & 1ull);
                if (b4 | (b2 & (sk == (int)neg))) fastfwd();
            }
        } else {                                              // CLAMP event at element js
            const float flen = (float)(js - k0 + 1);
            const float r = __builtin_amdgcn_rcpf(flen);
            const bool cmin = (un >= lam);
            const bool cmax = (ux <= mlam);
            vmin = cmin ? fmaf(un - lam, r, vmin) : vmin;
            km   = cmin ? js : km;
            umin = cmin ? lam : un;
            vmax = cmax ? fmaf(ux + lam, r, vmax) : vmax;
            kp   = cmax ? js : kp;
            umax = cmax ? mlam : ux;
            k = js;
        }
    }
}

// lean grid barrier: counter + generation, agent scope. Requires co-residency
// (guaranteed by cooperative launch) and cnt=gen=0 at kernel start (hipMemsetAsync).
__device__ __forceinline__ void gridbar(unsigned* cnt, unsigned* gen) {
    __syncthreads();
    if (threadIdx.x == 0) {
        __threadfence();                                         // release (agent)
        unsigned g = __hip_atomic_load(gen, __ATOMIC_RELAXED, __HIP_MEMORY_SCOPE_AGENT);
        unsigned a = __hip_atomic_fetch_add(cnt, 1u, __ATOMIC_RELAXED, __HIP_MEMORY_SCOPE_AGENT);
        if (a == NB - 1) {
            __hip_atomic_store(cnt, 0u, __ATOMIC_RELAXED, __HIP_MEMORY_SCOPE_AGENT);
            __hip_atomic_fetch_add(gen, 1u, __ATOMIC_RELEASE, __HIP_MEMORY_SCOPE_AGENT);
        } else {
            while (__hip_atomic_load(gen, __ATOMIC_RELAXED, __HIP_MEMORY_SCOPE_AGENT) == g)
                __builtin_amdgcn_s_sleep(1);
        }
        __threadfence();                                         // acquire (agent)
    }
    __syncthreads();
}

// Douglas-Rachford TV2D: wave w of block b owns column (4b+w) in phase 1 and row (4b+w)
// in phase 2. p (column-local) and q (row-local) persist in registers across iterations.
__global__ __launch_bounds__(NT) void tv2d_coop(const float* __restrict__ X,
                                                float* __restrict__ xw,   // = d_out
                                                float* __restrict__ y,
                                                unsigned* __restrict__ bar,  // [cnt, gen]
                                                unsigned* __restrict__ acc)  // [MAXIT]
{
    const int t = threadIdx.x;
    const int lane = t & 63;
    const int wave = t >> 6;
    const int line = blockIdx.x * NLINE + wave;

    Dist p = {0.f, 0.f, 0.f, 0.f};
    Dist q = {0.f, 0.f, 0.f, 0.f};

    for (int it = 0; it < MAXIT; ++it) {
        // ---- column phase: y = prox(x + p) on column `line`; p = v - y ----
        const float* xs = (it == 0) ? X : xw;
        const float* col = xs + line;
        Dist v, o;
        v.r0 = col[(4 * lane    ) * N] + p.r0;
        v.r1 = col[(4 * lane + 1) * N] + p.r1;
        v.r2 = col[(4 * lane + 2) * N] + p.r2;
        v.r3 = col[(4 * lane + 3) * N] + p.r3;
        tv1d_scan(v, o, lane);
        p.r0 = v.r0 - o.r0;  p.r1 = v.r1 - o.r1;
        p.r2 = v.r2 - o.r2;  p.r3 = v.r3 - o.r3;
        float* ycol = y + line;
        ycol[(4 * lane    ) * N] = o.r0;
        ycol[(4 * lane + 1) * N] = o.r1;
        ycol[(4 * lane + 2) * N] = o.r2;
        ycol[(4 * lane + 3) * N] = o.r3;
        gridbar(bar, bar + 1);

        // ---- row phase: x2 = prox(y + q) on row `line`; q = v - x2; acc = max|y-x2| ----
        Dist w, o2;
        const float4 yv = *(const float4*)(y + line * N + 4 * lane);
        w.r0 = yv.x + q.r0;
        w.r1 = yv.y + q.r1;
        w.r2 = yv.z + q.r2;
        w.r3 = yv.w + q.r3;
        tv1d_scan(w, o2, lane);
        float d0 = yv.x - o2.r0;    // y - x2
        float d1 = yv.y - o2.r1;
        float d2 = yv.z - o2.r2;
        float d3 = yv.w - o2.r3;
        q.r0 = w.r0 - o2.r0;  q.r1 = w.r1 - o2.r1;
        q.r2 = w.r2 - o2.r2;  q.r3 = w.r3 - o2.r3;
        float4 xv;
        xv.x = o2.r0; xv.y = o2.r1; xv.z = o2.r2; xv.w = o2.r3;
        *(float4*)(xw + line * N + 4 * lane) = xv;

        float am = fmaxf(fmaxf(fabsf(d0), fabsf(d1)), fmaxf(fabsf(d2), fabsf(d3)));
        #pragma unroll
        for (int off = 32; off > 0; off >>= 1)
            am = fmaxf(am, __shfl_xor(am, off));
        if (lane == 0) atomicMax(&acc[it], __float_as_uint(am));  // am>=0: uint order == float order
        gridbar(bar, bar + 1);

        unsigned a = __hip_atomic_load(&acc[it], __ATOMIC_RELAXED, __HIP_MEMORY_SCOPE_AGENT);
        if (__uint_as_float(a) < TOL) break;   // uniform across grid
    }
}

extern "C" void kernel_launch(void* const* d_in, const int* in_sizes, int n_in,
                              void* d_out, int out_size, void* d_ws, size_t ws_size,
                              hipStream_t stream) {
    const float* X = (const float*)d_in[0];
    float* xw = (float*)d_out;
    float* y = (float*)d_ws;
    unsigned* bar = (unsigned*)((char*)d_ws + (size_t)N * N * sizeof(float));
    unsigned* acc = bar + 2;
    // zero barrier state + per-iteration acc slots before the kernel (capture-legal)
    hipMemsetAsync((void*)bar, 0, (2 + MAXIT) * sizeof(unsigned), stream);
    void* args[] = { (void*)&X, (void*)&xw, (void*)&y, (void*)&bar, (void*)&acc };
    hipLaunchCooperativeKernel((void*)tv2d_coop, dim3(NB), dim3(NT), args, 0, stream);
}

// Round 9
// 411.259 us; speedup vs baseline: 1.3015x; 1.3015x over previous
//
#include <hip/hip_runtime.h>

#define N 256
#define NLINE 4               // lines (waves) per block
#define NB (N / NLINE)        // 64 blocks
#define NT (NLINE * 64)       // 256 threads
#define LAM 0.05f             // step = ALPHA/2
#define TWOLAM (2.0f * LAM)
#define FOURLAM (4.0f * LAM)
#define MAXIT 35
#define TOL 0.01f

// broadcast-read one lane's register (lane index is wave-uniform -> v_readlane)
__device__ __forceinline__ float rlane(float v, int lane) {
    return __int_as_float(__builtin_amdgcn_readlane(__float_as_int(v), lane));
}

// 256-float line distributed over the wave: element k lives in lane (k>>2), reg (k&3)
struct Dist { float r0, r1, r2, r3; };

// branchless fetch: 4 independent readlanes + 2 uniform selects
__device__ __forceinline__ float dfetch(const Dist& d, int k) {
    const int lane = k >> 2;
    const int sel = k & 3;
    float a = rlane(d.r0, lane);
    float b = rlane(d.r1, lane);
    float c = rlane(d.r2, lane);
    float e = rlane(d.r3, lane);
    float ab = (sel & 1) ? b : a;
    float ce = (sel & 1) ? e : c;
    return (sel & 2) ? ce : ab;
}

// O(1) segment flush: o[j] = val for j in [lo, hi]
__device__ __forceinline__ void flushseg(Dist& o, int lo, int hi, float val, int lane) {
    const unsigned len = (unsigned)(hi - lo);
    const int base = 4 * lane - lo;
    o.r0 = ((unsigned)(base    ) <= len) ? val : o.r0;
    o.r1 = ((unsigned)(base + 1) <= len) ? val : o.r1;
    o.r2 = ((unsigned)(base + 2) <= len) ? val : o.r2;
    o.r3 = ((unsigned)(base + 3) <= len) ? val : o.r3;
}

// scalar 4-way select of a 64-bit mask (s_cselect_b64)
__device__ __forceinline__ unsigned long long sel4(unsigned long long a, unsigned long long b,
                                                   unsigned long long c, unsigned long long d, int r) {
    unsigned long long ab = (r & 1) ? b : a;
    unsigned long long cd = (r & 1) ? d : c;
    return (r & 2) ? cd : ab;
}

// first element >= jmin among set bits of per-reg masks (element j = 4*lane + reg)
__device__ __forceinline__ int firstel(unsigned long long m0, unsigned long long m1,
                                       unsigned long long m2, unsigned long long m3, int jmin) {
    int best = 256;
    int L0 = (jmin + 3) >> 2;
    unsigned long long a0 = m0 & ((L0 >= 64) ? 0ull : (~0ull << L0));
    if (a0) { int el = 4 * (int)__builtin_ctzll(a0);     best = el < best ? el : best; }
    int L1 = (jmin + 2) >> 2;
    unsigned long long a1 = m1 & ((L1 >= 64) ? 0ull : (~0ull << L1));
    if (a1) { int el = 4 * (int)__builtin_ctzll(a1) + 1; best = el < best ? el : best; }
    int L2 = (jmin + 1) >> 2;
    unsigned long long a2 = m2 & ((L2 >= 64) ? 0ull : (~0ull << L2));
    if (a2) { int el = 4 * (int)__builtin_ctzll(a2) + 2; best = el < best ? el : best; }
    int L3 = (jmin    ) >> 2;
    unsigned long long a3 = m3 & ((L3 >= 64) ? 0ull : (~0ull << L3));
    if (a3) { int el = 4 * (int)__builtin_ctzll(a3) + 3; best = el < best ? el : best; }
    return best;
}

// Condat's exact 1D TV prox; wave-uniform control, register-resident line.
// R6 structure (cheap serial step + O(1) run fast-forward) with sign-aware run
// masks: forced jump at j given entry sign S[j-1]: |d|>4lam, or |d|>2lam same-dir.
__device__ void tv1d_scan(const Dist& v, Dist& o, const int lane)
{
    const float lam = LAM, mlam = -LAM, twolam = TWOLAM;

    // ---- per-scan precompute (vectorized) ----
    Dist vnx;                                    // vnx[j] = v[j+1] (j=255 garbage)
    vnx.r0 = v.r1; vnx.r1 = v.r2; vnx.r2 = v.r3;
    vnx.r3 = __shfl_down(v.r0, 1);
    Dist d;
    d.r0 = vnx.r0 - v.r0;  d.r1 = vnx.r1 - v.r1;
    d.r2 = vnx.r2 - v.r2;  d.r3 = vnx.r3 - v.r3;
    const unsigned lambits = __float_as_uint(lam);
    Dist sl;                                     // sl[j] = sign(d[j]) * lam
    sl.r0 = __uint_as_float((__float_as_uint(d.r0) & 0x80000000u) | lambits);
    sl.r1 = __uint_as_float((__float_as_uint(d.r1) & 0x80000000u) | lambits);
    sl.r2 = __uint_as_float((__float_as_uint(d.r2) & 0x80000000u) | lambits);
    sl.r3 = __uint_as_float((__float_as_uint(d.r3) & 0x80000000u) | lambits);
    Dist slp;                                    // slp[j] = sl[j-1], slp[0] = 0
    slp.r1 = sl.r0; slp.r2 = sl.r1; slp.r3 = sl.r2;
    {
        float s3u = __shfl_up(sl.r3, 1);
        slp.r0 = (lane == 0) ? 0.0f : s3u;
    }
    Dist e;                                      // e[j] = v[j] + sl[j] - slp[j]
    e.r0 = v.r0 + sl.r0 - slp.r0;
    e.r1 = v.r1 + sl.r1 - slp.r1;
    e.r2 = v.r2 + sl.r2 - slp.r2;
    e.r3 = v.r3 + sl.r3 - slp.r3;
    const unsigned long long S0 = __ballot(d.r0 < 0.0f);
    const unsigned long long S1 = __ballot(d.r1 < 0.0f);
    const unsigned long long S2 = __ballot(d.r2 < 0.0f);
    const unsigned long long S3 = __ballot(d.r3 < 0.0f);
    const unsigned long long B2_0 = __ballot(fabsf(d.r0) > TWOLAM);
    const unsigned long long B2_1 = __ballot(fabsf(d.r1) > TWOLAM);
    const unsigned long long B2_2 = __ballot(fabsf(d.r2) > TWOLAM);
    const unsigned long long B2_3 = __ballot(fabsf(d.r3) > TWOLAM);
    const unsigned long long B4_0 = __ballot(fabsf(d.r0) > FOURLAM);
    const unsigned long long B4_1 = __ballot(fabsf(d.r1) > FOURLAM);
    const unsigned long long B4_2 = __ballot(fabsf(d.r2) > FOURLAM);
    const unsigned long long B4_3 = __ballot(fabsf(d.r3) > FOURLAM);
    // run-continuation (entry sign at j is S[j-1]):  F = B4 | (B2 & ~(S ^ Sprev))
    const unsigned long long Sp0 = (S3 << 1);    // j=0 bit irrelevant (never searched)
    const unsigned long long Sp1 = S0, Sp2 = S1, Sp3 = S2;
    const unsigned long long NF0 = ~(B4_0 | (B2_0 & ~(S0 ^ Sp0)));
    const unsigned long long NF1 = ~(B4_1 | (B2_1 & ~(S1 ^ Sp1)));
    const unsigned long long NF2 = ~(B4_2 | (B2_2 & ~(S2 ^ Sp2)));
    const unsigned long long NF3 = ~((B4_3 | (B2_3 & ~(S3 ^ Sp3))) & 0x7FFFFFFFFFFFFFFFull); // 255 never forced

    // ---- serial state ----
    int k = 0, k0 = 0, km = 0, kp = 0;
    float umin = lam, umax = mlam;
    const float v0 = rlane(v.r0, 0);
    float vmin = v0 - lam, vmax = v0 + lam;
    float flen = 1.0f;                  // = k - k0 + 1
    float vn1 = dfetch(v, 1);           // v[k+1]
    float vn2 = dfetch(v, 2);           // v[k+2] (clamped at boundary)
    int guard = 0;

    // pre: fresh state at k, jump at next step forced with direction S[k], k <= N-2
    auto fastfwd = [&]() {
        const int K1 = firstel(NF0, NF1, NF2, NF3, k + 1);    // first non-forced j > k (<= 255)
        const int sneg = (int)((sel4(S0, S1, S2, S3, k & 3) >> (k >> 2)) & 1ull);
        flushseg(o, k, k, sneg ? vmin : vmax, lane);          // first run element
        if (K1 > k + 1) {                                     // (k, K1-1]: closed-form e[j]
            const int lo = k + 1;
            const unsigned len = (unsigned)(K1 - 1 - lo);
            const int base = 4 * lane - lo;
            o.r0 = ((unsigned)(base    ) <= len) ? e.r0 : o.r0;
            o.r1 = ((unsigned)(base + 1) <= len) ? e.r1 : o.r1;
            o.r2 = ((unsigned)(base + 2) <= len) ? e.r2 : o.r2;
            o.r3 = ((unsigned)(base + 3) <= len) ? e.r3 : o.r3;
        }
        k = K1; k0 = K1; km = K1; kp = K1;                    // fresh at K1, entry sign = S[K1-1]
        const float vK = dfetch(v, K1);
        const float sp = dfetch(slp, K1);                     // = sl[K1-1]
        vmin = vK - lam - sp;
        vmax = vmin + twolam;
        umin = lam; umax = mlam;
        flen = 1.0f;
        if (K1 < N - 1) {
            vn1 = dfetch(v, K1 + 1);
            vn2 = dfetch(v, (K1 + 2 <= N - 1) ? K1 + 2 : N - 1);
        }
    };

    auto do_step = [&]() {
        const int kpre = (k + 3 <= N - 1) ? k + 3 : N - 1;
        const float vnn = dfetch(v, kpre);           // speculative v[k+3], off-chain
        const float un = umin + vn1 - vmin;
        const float ux = umax + vn1 - vmax;
        const bool neg = un < mlam;
        const bool pos = ux > lam;
        if (__builtin_expect((int)(neg | pos), 1)) {     // JUMP
            const float fval = neg ? vmin : vmax;
            const int   fhi  = neg ? km : kp;
            flushseg(o, k0, fhi, fval, lane);
            k0 = fhi + 1;
            float vstar, w1, w2;
            if (__builtin_expect((int)(k0 <= k), 0)) {   // rewind (rare)
                vstar = dfetch(v, k0);
                w1 = dfetch(v, (k0 + 1 <= N - 1) ? k0 + 1 : N - 1);
                w2 = dfetch(v, (k0 + 2 <= N - 1) ? k0 + 2 : N - 1);
            } else {                                     // fresh: rename only
                vstar = vn1; w1 = vn2; w2 = vnn;
            }
            vn1 = w1; vn2 = w2;
            k = k0; km = k0; kp = k0;
            vmin = neg ? vstar : vstar - twolam;
            vmax = vmin + twolam;
            umin = lam; umax = mlam;
            flen = 1.0f;
            if (k < N - 1) {                             // sign-aware run trigger
                const int kb = k >> 2, kr = k & 3;
                const int b4 = (int)((sel4(B4_0, B4_1, B4_2, B4_3, kr) >> kb) & 1ull);
                const int b2 = (int)((sel4(B2_0, B2_1, B2_2, B2_3, kr) >> kb) & 1ull);
                const int sk = (int)((sel4(S0, S1, S2, S3, kr) >> kb) & 1ull);
                if (b4 | (b2 & (sk == (int)neg))) fastfwd();
            }
        } else {                                         // no jump (predicated)
            k++;
            flen += 1.0f;
            const float r = __builtin_amdgcn_rcpf(flen);
            const bool cmin = (un >= lam);
            const bool cmax = (ux <= mlam);
            vmin = cmin ? fmaf(un - lam, r, vmin) : vmin;
            km   = cmin ? k : km;
            umin = cmin ? lam : un;
            vmax = cmax ? fmaf(ux + lam, r, vmax) : vmax;
            kp   = cmax ? k : kp;
            umax = cmax ? mlam : ux;
            vn1 = vn2; vn2 = vnn;
        }
    };

    // init: jump at element 1 forced iff |d0| > 3lam; use conservative 4lam bit
    if ((int)(B4_0 & 1ull)) fastfwd();

    for (;;) {
        while (k < N - 1) {
            if (++guard > 2000) return; // provably terminates; belt+suspenders
            do_step();
            if (k >= N - 1) break;
            do_step();
        }
        // boundary resolution at k == N-1 (verbatim semantics from verified R2/R6)
        for (;;) {
            if (++guard > 4000) return;
            if (umin < 0.0f) {
                flushseg(o, k0, km, vmin, lane);
                k0 = km + 1;
                if (k0 > N - 1) return;
                km = k = k0;
                vmin = dfetch(v, k0);
                umin = lam;
                umax = vmin + lam - vmax;
                flen = 1.0f;
            } else if (umax > 0.0f) {
                flushseg(o, k0, kp, vmax, lane);
                k0 = kp + 1;
                if (k0 > N - 1) return;
                kp = k = k0;
                vmax = dfetch(v, k0);
                umax = mlam;
                umin = vmax - lam - vmin;
                flen = 1.0f;
            } else {
                vmin += umin / (float)(k - k0 + 1);
                flushseg(o, k0, k, vmin, lane);
                return;
            }
            if (k != N - 1) break;
        }
        vn1 = dfetch(v, k + 1);
        vn2 = dfetch(v, (k + 2 <= N - 1) ? k + 2 : N - 1);
    }
}

// flag-array grid barrier: block b stores flags[b]=seq (after device fence); every
// block's wave 0 polls all 64 flags with one coalesced 64-lane load. No central
// counter RMW, no generation propagation hop. Needs co-residency (coop launch)
// and flags zeroed at launch (hipMemsetAsync); seq strictly increasing.
__device__ __forceinline__ void gridbar(unsigned* flags, unsigned seq, int t) {
    __syncthreads();
    __threadfence();
    if (t == 0)
        __hip_atomic_store(&flags[blockIdx.x], seq, __ATOMIC_RELAXED, __HIP_MEMORY_SCOPE_AGENT);
    if (t < 64) {
        for (;;) {
            unsigned f = __hip_atomic_load(&flags[t], __ATOMIC_RELAXED, __HIP_MEMORY_SCOPE_AGENT);
            if (__all((int)(f >= seq))) break;
            __builtin_amdgcn_s_sleep(1);
        }
    }
    __threadfence();
    __syncthreads();
}

// Douglas-Rachford TV2D: wave w of block b owns column (4b+w) in phase 1 and row
// (4b+w) in phase 2. p, q persist in registers across iterations.
__global__ __launch_bounds__(NT) void tv2d_coop(const float* __restrict__ X,
                                                float* __restrict__ xw,     // = d_out
                                                float* __restrict__ y,
                                                unsigned* __restrict__ flags,  // [NB]
                                                unsigned* __restrict__ bm)     // [NB] per-block max
{
    const int t = threadIdx.x;
    const int lane = t & 63;
    const int wave = t >> 6;
    const int line = blockIdx.x * NLINE + wave;
    __shared__ unsigned s_acc;
    __shared__ int s_dec;
    if (t == 0) s_acc = 0u;

    Dist p = {0.f, 0.f, 0.f, 0.f};
    Dist q = {0.f, 0.f, 0.f, 0.f};

    for (int it = 0; it < MAXIT; ++it) {
        // ---- column phase: y = prox(x + p) on column `line`; p = v - y ----
        const float* xs = (it == 0) ? X : xw;
        const float* col = xs + line;
        Dist v, o;
        v.r0 = col[(4 * lane    ) * N] + p.r0;
        v.r1 = col[(4 * lane + 1) * N] + p.r1;
        v.r2 = col[(4 * lane + 2) * N] + p.r2;
        v.r3 = col[(4 * lane + 3) * N] + p.r3;
        tv1d_scan(v, o, lane);
        p.r0 = v.r0 - o.r0;  p.r1 = v.r1 - o.r1;
        p.r2 = v.r2 - o.r2;  p.r3 = v.r3 - o.r3;
        float* ycol = y + line;
        ycol[(4 * lane    ) * N] = o.r0;
        ycol[(4 * lane + 1) * N] = o.r1;
        ycol[(4 * lane + 2) * N] = o.r2;
        ycol[(4 * lane + 3) * N] = o.r3;
        gridbar(flags, 2u * (unsigned)it + 1u, t);

        // ---- row phase: x2 = prox(y + q) on row `line`; q = v - x2; acc = max|y-x2| ----
        Dist w, o2;
        const float4 yv = *(const float4*)(y + line * N + 4 * lane);
        w.r0 = yv.x + q.r0;
        w.r1 = yv.y + q.r1;
        w.r2 = yv.z + q.r2;
        w.r3 = yv.w + q.r3;
        tv1d_scan(w, o2, lane);
        float d0 = yv.x - o2.r0;    // y - x2
        float d1 = yv.y - o2.r1;
        float d2 = yv.z - o2.r2;
        float d3 = yv.w - o2.r3;
        q.r0 = w.r0 - o2.r0;  q.r1 = w.r1 - o2.r1;
        q.r2 = w.r2 - o2.r2;  q.r3 = w.r3 - o2.r3;
        float4 xv;
        xv.x = o2.r0; xv.y = o2.r1; xv.z = o2.r2; xv.w = o2.r3;
        *(float4*)(xw + line * N + 4 * lane) = xv;

        float am = fmaxf(fmaxf(fabsf(d0), fabsf(d1)), fmaxf(fabsf(d2), fabsf(d3)));
        #pragma unroll
        for (int off = 32; off > 0; off >>= 1)
            am = fmaxf(am, __shfl_xor(am, off));
        if (lane == 0) atomicMax(&s_acc, __float_as_uint(am));   // LDS atomic, 4/block

        // ---- barrier 2 with per-block max payload + uniform convergence decision ----
        const unsigned seq2 = 2u * (unsigned)it + 2u;
        __syncthreads();                                          // s_acc complete
        if (t == 0)
            __hip_atomic_store(&bm[blockIdx.x], s_acc, __ATOMIC_RELAXED, __HIP_MEMORY_SCOPE_AGENT);
        __threadfence();                                          // y/x2/bm visible before flag
        if (t == 0)
            __hip_atomic_store(&flags[blockIdx.x], seq2, __ATOMIC_RELAXED, __HIP_MEMORY_SCOPE_AGENT);
        if (t < 64) {
            for (;;) {
                unsigned f = __hip_atomic_load(&flags[t], __ATOMIC_RELAXED, __HIP_MEMORY_SCOPE_AGENT);
                if (__all((int)(f >= seq2))) break;
                __builtin_amdgcn_s_sleep(1);
            }
        }
        __threadfence();
        if (t < 64) {
            unsigned m = __hip_atomic_load(&bm[t], __ATOMIC_RELAXED, __HIP_MEMORY_SCOPE_AGENT);
            #pragma unroll
            for (int off = 32; off > 0; off >>= 1) {
                unsigned mm = __shfl_xor(m, off);
                m = (mm > m) ? mm : m;                            // am>=0: uint order == float order
            }
            if (t == 0) { s_dec = (__uint_as_float(m) < TOL) ? 1 : 0; s_acc = 0u; }
        }
        __syncthreads();
        if (s_dec) break;                                         // uniform across grid
    }
}

extern "C" void kernel_launch(void* const* d_in, const int* in_sizes, int n_in,
                              void* d_out, int out_size, void* d_ws, size_t ws_size,
                              hipStream_t stream) {
    const float* X = (const float*)d_in[0];
    float* xw = (float*)d_out;
    float* y = (float*)d_ws;
    unsigned* flags = (unsigned*)((char*)d_ws + (size_t)N * N * sizeof(float));
    unsigned* bm = flags + 64;
    // zero the flag array before the kernel (capture-legal); bm written before read
    (void)hipMemsetAsync((void*)flags, 0, NB * sizeof(unsigned), stream);
    void* args[] = { (void*)&X, (void*)&xw, (void*)&y, (void*)&flags, (void*)&bm };
    (void)hipLaunchCooperativeKernel((void*)tv2d_coop, dim3(NB), dim3(NT), args, 0, stream);
}

// Round 11
// 370.478 us; speedup vs baseline: 1.4448x; 1.1101x over previous
//
#include <hip/hip_runtime.h>

#define N 256
#define NLINE 4               // lines (waves) per block
#define NB (N / NLINE)        // 64 blocks
#define NT (NLINE * 64)       // 256 threads
#define LAM 0.05f             // step = ALPHA/2
#define TWOLAM (2.0f * LAM)
#define FOURLAM (4.0f * LAM)
#define MAXIT 35
#define TOL 0.01f

// broadcast-read one lane's register (lane index is wave-uniform -> v_readlane)
__device__ __forceinline__ float rlane(float v, int lane) {
    return __int_as_float(__builtin_amdgcn_readlane(__float_as_int(v), lane));
}

// 256-float line distributed over the wave: element k lives in lane (k&63), reg (k>>6)
// -> ballot words are CONTIGUOUS 64-element spans (word w = elements 64w..64w+63)
struct Dist { float r0, r1, r2, r3; };

// branchless fetch: 4 independent readlanes + 2 uniform selects
__device__ __forceinline__ float dfetch(const Dist& d, int k) {
    const int lane = k & 63;
    const int sel = k >> 6;
    float a = rlane(d.r0, lane);
    float b = rlane(d.r1, lane);
    float c = rlane(d.r2, lane);
    float e = rlane(d.r3, lane);
    float ab = (sel & 1) ? b : a;
    float ce = (sel & 1) ? e : c;
    return (sel & 2) ? ce : ab;
}

// O(1) segment flush: o[j] = val for j in [lo, hi]; element j of reg r = 64r + lane
__device__ __forceinline__ void flushseg(Dist& o, int lo, int hi, float val, int lane) {
    const unsigned len = (unsigned)(hi - lo);
    const int base = lane - lo;
    o.r0 = ((unsigned)(base      ) <= len) ? val : o.r0;
    o.r1 = ((unsigned)(base + 64 ) <= len) ? val : o.r1;
    o.r2 = ((unsigned)(base + 128) <= len) ? val : o.r2;
    o.r3 = ((unsigned)(base + 192) <= len) ? val : o.r3;
}

// scalar 4-way select of a 64-bit mask (s_cselect_b64)
__device__ __forceinline__ unsigned long long sel4(unsigned long long a, unsigned long long b,
                                                   unsigned long long c, unsigned long long d, int r) {
    unsigned long long ab = (r & 1) ? b : a;
    unsigned long long cd = (r & 1) ? d : c;
    return (r & 2) ? cd : ab;
}

// Condat's exact 1D TV prox; wave-uniform control, register-resident line.
// R9 structure (cheap serial step + O(1) sign-aware run fast-forward), with:
// contiguous mask words (fast firstnf), precomputed g[] (1-dfetch FF exit),
// precomputed FNneg/FNpos trigger masks, single-register value pipeline.
// BUGFIX vs R10: fastfwd's first-element flush uses EXIT direction sign(d[k])
// (looked up from S masks), not the entry direction.
__device__ void tv1d_scan(const Dist& v, Dist& o, const int lane)
{
    const float lam = LAM, mlam = -LAM, twolam = TWOLAM;

    // ---- per-scan precompute (vectorized) ----
    Dist vnx;                                    // vnx[j] = v[j+1] (j=255 garbage)
    {
        float a0 = __shfl_down(v.r0, 1), a1 = __shfl_down(v.r1, 1);
        float a2 = __shfl_down(v.r2, 1), a3 = __shfl_down(v.r3, 1);
        const bool hi = (lane == 63);
        vnx.r0 = hi ? rlane(v.r1, 0) : a0;
        vnx.r1 = hi ? rlane(v.r2, 0) : a1;
        vnx.r2 = hi ? rlane(v.r3, 0) : a2;
        vnx.r3 = a3;
    }
    Dist d;
    d.r0 = vnx.r0 - v.r0;  d.r1 = vnx.r1 - v.r1;
    d.r2 = vnx.r2 - v.r2;  d.r3 = vnx.r3 - v.r3;
    const unsigned lambits = __float_as_uint(lam);
    Dist sl;                                     // sl[j] = sign(d[j]) * lam
    sl.r0 = __uint_as_float((__float_as_uint(d.r0) & 0x80000000u) | lambits);
    sl.r1 = __uint_as_float((__float_as_uint(d.r1) & 0x80000000u) | lambits);
    sl.r2 = __uint_as_float((__float_as_uint(d.r2) & 0x80000000u) | lambits);
    sl.r3 = __uint_as_float((__float_as_uint(d.r3) & 0x80000000u) | lambits);
    Dist slp;                                    // slp[j] = sl[j-1], slp[0] = 0
    {
        float b0 = __shfl_up(sl.r0, 1), b1 = __shfl_up(sl.r1, 1);
        float b2 = __shfl_up(sl.r2, 1), b3 = __shfl_up(sl.r3, 1);
        const bool lo = (lane == 0);
        slp.r0 = lo ? 0.0f : b0;
        slp.r1 = lo ? rlane(sl.r0, 63) : b1;
        slp.r2 = lo ? rlane(sl.r1, 63) : b2;
        slp.r3 = lo ? rlane(sl.r2, 63) : b3;
    }
    Dist e, g;                                   // e[j] = v[j]+sl[j]-slp[j]; g[j] = v[j]-lam-slp[j]
    {
        float t0 = v.r0 - slp.r0, t1 = v.r1 - slp.r1, t2 = v.r2 - slp.r2, t3 = v.r3 - slp.r3;
        e.r0 = t0 + sl.r0;  e.r1 = t1 + sl.r1;  e.r2 = t2 + sl.r2;  e.r3 = t3 + sl.r3;
        g.r0 = t0 - lam;    g.r1 = t1 - lam;    g.r2 = t2 - lam;    g.r3 = t3 - lam;
    }
    const unsigned long long S0 = __ballot(d.r0 < 0.0f);
    const unsigned long long S1 = __ballot(d.r1 < 0.0f);
    const unsigned long long S2 = __ballot(d.r2 < 0.0f);
    const unsigned long long S3 = __ballot(d.r3 < 0.0f);
    const unsigned long long B20 = __ballot(fabsf(d.r0) > TWOLAM);
    const unsigned long long B21 = __ballot(fabsf(d.r1) > TWOLAM);
    const unsigned long long B22 = __ballot(fabsf(d.r2) > TWOLAM);
    const unsigned long long B23 = __ballot(fabsf(d.r3) > TWOLAM);
    const unsigned long long B40 = __ballot(fabsf(d.r0) > FOURLAM);
    const unsigned long long B41 = __ballot(fabsf(d.r1) > FOURLAM);
    const unsigned long long B42 = __ballot(fabsf(d.r2) > FOURLAM);
    const unsigned long long B43 = __ballot(fabsf(d.r3) > FOURLAM);
    // Sprev shifts S by one element across contiguous words
    const unsigned long long Sp0 = (S0 << 1);
    const unsigned long long Sp1 = (S1 << 1) | (S0 >> 63);
    const unsigned long long Sp2 = (S2 << 1) | (S1 >> 63);
    const unsigned long long Sp3 = (S3 << 1) | (S2 >> 63);
    // run-continuation: F = B4 | (B2 & same-sign-as-prev); NF = ~F (element 255 never forced)
    const unsigned long long NF0 = ~(B40 | (B20 & ~(S0 ^ Sp0)));
    const unsigned long long NF1 = ~(B41 | (B21 & ~(S1 ^ Sp1)));
    const unsigned long long NF2 = ~(B42 | (B22 & ~(S2 ^ Sp2)));
    const unsigned long long NF3 = ~((B43 | (B23 & ~(S3 ^ Sp3))) & 0x7FFFFFFFFFFFFFFFull);
    // post-jump trigger masks by ENTRY direction (threshold: same-dir 2lam, opposite 4lam)
    const unsigned long long FNn0 = (S0 & B20) | (~S0 & B40);
    const unsigned long long FNn1 = (S1 & B21) | (~S1 & B41);
    const unsigned long long FNn2 = (S2 & B22) | (~S2 & B42);
    const unsigned long long FNn3 = (S3 & B23) | (~S3 & B43);
    const unsigned long long FNp0 = (~S0 & B20) | (S0 & B40);
    const unsigned long long FNp1 = (~S1 & B21) | (S1 & B41);
    const unsigned long long FNp2 = (~S2 & B22) | (S2 & B42);
    const unsigned long long FNp3 = (~S3 & B23) | (S3 & B43);
    const int initFF = (int)(B40 & 1ull);        // conservative (|d0|>4lam => forced first jump)

    // first non-forced element >= jmin (fast path: same word)
    auto firstnf = [&](int jmin) -> int {
        const int w = jmin >> 6;
        unsigned long long m = sel4(NF0, NF1, NF2, NF3, w) >> (jmin & 63);
        if (m) return jmin + (int)__builtin_ctzll(m);
        unsigned long long m1 = (w < 1) ? NF1 : 0ull;
        unsigned long long m2 = (w < 2) ? NF2 : 0ull;
        if (m1) return 64 + (int)__builtin_ctzll(m1);
        if (m2) return 128 + (int)__builtin_ctzll(m2);
        return 192 + (int)__builtin_ctzll(NF3);  // NF3 bit63 always set -> reachable & nonzero
    };

    auto trigbit = [&](int kk, int neg) -> int {
        const int w = kk >> 6;
        const unsigned long long m = neg ? sel4(FNn0, FNn1, FNn2, FNn3, w)
                                         : sel4(FNp0, FNp1, FNp2, FNp3, w);
        return (int)((m >> (kk & 63)) & 1ull);
    };

    // ---- serial state ----
    int k = 0, k0 = 0, km = 0, kp = 0;
    float umin = lam, umax = mlam;
    const float v0 = rlane(v.r0, 0);
    float vmin = v0 - lam, vmax = v0 + lam;
    float flen = 1.0f;                  // = k - k0 + 1
    float vn1 = dfetch(v, 1);           // v[k+1]
    int guard = 0;

    // pre: standard-fresh at k (=k0=km=kp), next jump forced, k <= N-2.
    // EXIT direction = sign(d[k]) is looked up here (NOT the entry direction).
    auto fastfwd = [&]() {
        const int K1 = firstnf(k + 1);                        // first non-forced j > k (<= 255)
        const int sneg = (int)((sel4(S0, S1, S2, S3, k >> 6) >> (k & 63)) & 1ull); // sign(d[k])
        flushseg(o, k, k, sneg ? vmin : vmax, lane);          // first run element
        if (K1 > k + 1) {                                     // (k, K1-1]: closed-form e[j]
            const int lo = k + 1;
            const unsigned len = (unsigned)(K1 - 1 - lo);
            const int base = lane - lo;
            o.r0 = ((unsigned)(base      ) <= len) ? e.r0 : o.r0;
            o.r1 = ((unsigned)(base + 64 ) <= len) ? e.r1 : o.r1;
            o.r2 = ((unsigned)(base + 128) <= len) ? e.r2 : o.r2;
            o.r3 = ((unsigned)(base + 192) <= len) ? e.r3 : o.r3;
        }
        k = K1; k0 = K1; km = K1; kp = K1;                    // fresh at K1, entry sign = S[K1-1]
        vmin = dfetch(g, K1);                                 // = v[K1] - lam - sl[K1-1]
        vmax = vmin + twolam;
        umin = lam; umax = mlam;
        flen = 1.0f;
        vn1 = dfetch(v, (K1 < N - 1) ? K1 + 1 : N - 1);
    };

    auto do_step = [&]() {
        const float un = umin + vn1 - vmin;
        const float ux = umax + vn1 - vmax;
        const bool neg = un < mlam;
        const bool pos = ux > lam;
        if (__builtin_expect((int)(neg | pos), 1)) {          // JUMP
            const float fval = neg ? vmin : vmax;
            const int   fhi  = neg ? km : kp;
            flushseg(o, k0, fhi, fval, lane);
            const int k0n = fhi + 1;
            float vstar;
            if (__builtin_expect((int)(k0n <= k), 0)) vstar = dfetch(v, k0n);  // rewind (rare)
            else                                      vstar = vn1;             // fresh: rename
            k = k0n; k0 = k0n; km = k0n; kp = k0n;
            vmin = neg ? vstar : vstar - twolam;
            vmax = vmin + twolam;
            umin = lam; umax = mlam;
            flen = 1.0f;
            if (k < N - 1 && trigbit(k, (int)neg)) {
                fastfwd();                                    // run of guaranteed jumps
            } else {
                vn1 = dfetch(v, (k < N - 1) ? k + 1 : N - 1);
            }
        } else {                                              // no jump (predicated)
            k++;
            flen += 1.0f;
            const float r = __builtin_amdgcn_rcpf(flen);
            const bool cmin = (un >= lam);
            const bool cmax = (ux <= mlam);
            vmin = cmin ? fmaf(un - lam, r, vmin) : vmin;
            km   = cmin ? k : km;
            umin = cmin ? lam : un;
            vmax = cmax ? fmaf(ux + lam, r, vmax) : vmax;
            kp   = cmax ? k : kp;
            umax = cmax ? mlam : ux;
            vn1 = dfetch(v, (k < N - 1) ? k + 1 : N - 1);
        }
    };

    if (initFF) fastfwd();

    for (;;) {
        while (k < N - 1) {
            if (++guard > 2000) return; // provably terminates; belt+suspenders
            do_step();
            if (k >= N - 1) break;
            do_step();
        }
        // boundary resolution at k == N-1 (verbatim semantics from verified R2/R6)
        for (;;) {
            if (++guard > 4000) return;
            if (umin < 0.0f) {
                flushseg(o, k0, km, vmin, lane);
                k0 = km + 1;
                if (k0 > N - 1) return;
                km = k = k0;
                vmin = dfetch(v, k0);
                umin = lam;
                umax = vmin + lam - vmax;
                flen = 1.0f;
            } else if (umax > 0.0f) {
                flushseg(o, k0, kp, vmax, lane);
                k0 = kp + 1;
                if (k0 > N - 1) return;
                kp = k = k0;
                vmax = dfetch(v, k0);
                umax = mlam;
                umin = vmax - lam - vmin;
                flen = 1.0f;
            } else {
                vmin += umin / flen;
                flushseg(o, k0, k, vmin, lane);
                return;
            }
            if (k != N - 1) break;
        }
        vn1 = dfetch(v, k + 1);
    }
}

// flag-array grid barrier: block b stores flags[b]=seq (after device fence); every
// block's wave 0 polls all 64 flags with one coalesced 64-lane load. Needs
// co-residency (coop launch) and flags zeroed at launch; seq strictly increasing.
__device__ __forceinline__ void gridbar(unsigned* flags, unsigned seq, int t) {
    __syncthreads();
    __threadfence();
    if (t == 0)
        __hip_atomic_store(&flags[blockIdx.x], seq, __ATOMIC_RELAXED, __HIP_MEMORY_SCOPE_AGENT);
    if (t < 64) {
        for (;;) {
            unsigned f = __hip_atomic_load(&flags[t], __ATOMIC_RELAXED, __HIP_MEMORY_SCOPE_AGENT);
            if (__all((int)(f >= seq))) break;
            __builtin_amdgcn_s_sleep(1);
        }
    }
    __threadfence();
    __syncthreads();
}

// Douglas-Rachford TV2D: wave w of block b owns column (4b+w) in phase 1 and row
// (4b+w) in phase 2. p, q persist in registers across iterations.
__global__ __launch_bounds__(NT) void tv2d_coop(const float* __restrict__ X,
                                                float* __restrict__ xw,     // = d_out
                                                float* __restrict__ y,
                                                unsigned* __restrict__ flags,  // [NB]
                                                unsigned* __restrict__ bm)     // [NB] per-block max
{
    const int t = threadIdx.x;
    const int lane = t & 63;
    const int wave = t >> 6;
    const int line = blockIdx.x * NLINE + wave;
    __shared__ unsigned s_acc;
    __shared__ int s_dec;
    if (t == 0) s_acc = 0u;

    Dist p = {0.f, 0.f, 0.f, 0.f};
    Dist q = {0.f, 0.f, 0.f, 0.f};

    for (int it = 0; it < MAXIT; ++it) {
        // ---- column phase: y = prox(x + p) on column `line`; p = v - y ----
        const float* xs = (it == 0) ? X : xw;
        const float* col = xs + line;
        Dist v, o;
        v.r0 = col[(lane      ) * N] + p.r0;
        v.r1 = col[(lane + 64 ) * N] + p.r1;
        v.r2 = col[(lane + 128) * N] + p.r2;
        v.r3 = col[(lane + 192) * N] + p.r3;
        tv1d_scan(v, o, lane);
        p.r0 = v.r0 - o.r0;  p.r1 = v.r1 - o.r1;
        p.r2 = v.r2 - o.r2;  p.r3 = v.r3 - o.r3;
        float* ycol = y + line;
        ycol[(lane      ) * N] = o.r0;
        ycol[(lane + 64 ) * N] = o.r1;
        ycol[(lane + 128) * N] = o.r2;
        ycol[(lane + 192) * N] = o.r3;
        gridbar(flags, 2u * (unsigned)it + 1u, t);

        // ---- row phase: x2 = prox(y + q) on row `line`; q = v - x2; acc = max|y-x2| ----
        const float* yr = y + line * N;
        float y0 = yr[lane      ];
        float y1 = yr[lane + 64 ];
        float y2 = yr[lane + 128];
        float y3 = yr[lane + 192];
        Dist w, o2;
        w.r0 = y0 + q.r0;
        w.r1 = y1 + q.r1;
        w.r2 = y2 + q.r2;
        w.r3 = y3 + q.r3;
        tv1d_scan(w, o2, lane);
        float d0 = y0 - o2.r0;    // y - x2
        float d1 = y1 - o2.r1;
        float d2 = y2 - o2.r2;
        float d3 = y3 - o2.r3;
        q.r0 = w.r0 - o2.r0;  q.r1 = w.r1 - o2.r1;
        q.r2 = w.r2 - o2.r2;  q.r3 = w.r3 - o2.r3;
        float* xr = xw + line * N;
        xr[lane      ] = o2.r0;
        xr[lane + 64 ] = o2.r1;
        xr[lane + 128] = o2.r2;
        xr[lane + 192] = o2.r3;

        float am = fmaxf(fmaxf(fabsf(d0), fabsf(d1)), fmaxf(fabsf(d2), fabsf(d3)));
        #pragma unroll
        for (int off = 32; off > 0; off >>= 1)
            am = fmaxf(am, __shfl_xor(am, off));
        if (lane == 0) atomicMax(&s_acc, __float_as_uint(am));   // LDS atomic, 4/block

        // ---- barrier 2 with per-block max payload + uniform convergence decision ----
        const unsigned seq2 = 2u * (unsigned)it + 2u;
        __syncthreads();                                          // s_acc complete
        if (t == 0)
            __hip_atomic_store(&bm[blockIdx.x], s_acc, __ATOMIC_RELAXED, __HIP_MEMORY_SCOPE_AGENT);
        __threadfence();                                          // y/x2/bm visible before flag
        if (t == 0)
            __hip_atomic_store(&flags[blockIdx.x], seq2, __ATOMIC_RELAXED, __HIP_MEMORY_SCOPE_AGENT);
        if (t < 64) {
            for (;;) {
                unsigned f = __hip_atomic_load(&flags[t], __ATOMIC_RELAXED, __HIP_MEMORY_SCOPE_AGENT);
                if (__all((int)(f >= seq2))) break;
                __builtin_amdgcn_s_sleep(1);
            }
        }
        __threadfence();
        if (t < 64) {
            unsigned m = __hip_atomic_load(&bm[t], __ATOMIC_RELAXED, __HIP_MEMORY_SCOPE_AGENT);
            #pragma unroll
            for (int off = 32; off > 0; off >>= 1) {
                unsigned mm = __shfl_xor(m, off);
                m = (mm > m) ? mm : m;                            // am>=0: uint order == float order
            }
            if (t == 0) { s_dec = (__uint_as_float(m) < TOL) ? 1 : 0; s_acc = 0u; }
        }
        __syncthreads();
        if (s_dec) break;                                         // uniform across grid
    }
}

extern "C" void kernel_launch(void* const* d_in, const int* in_sizes, int n_in,
                              void* d_out, int out_size, void* d_ws, size_t ws_size,
                              hipStream_t stream) {
    const float* X = (const float*)d_in[0];
    float* xw = (float*)d_out;
    float* y = (float*)d_ws;
    unsigned* flags = (unsigned*)((char*)d_ws + (size_t)N * N * sizeof(float));
    unsigned* bm = flags + 64;
    // zero the flag array before the kernel (capture-legal); bm written before read
    (void)hipMemsetAsync((void*)flags, 0, NB * sizeof(unsigned), stream);
    void* args[] = { (void*)&X, (void*)&xw, (void*)&y, (void*)&flags, (void*)&bm };
    (void)hipLaunchCooperativeKernel((void*)tv2d_coop, dim3(NB), dim3(NT), args, 0, stream);
}